// Round 14
// baseline (721.732 us; speedup 1.0000x reference)
//
#include <hip/hip_runtime.h>
#include <cstddef>

#define BB   256    // batch = GEMM1 M
#define UU   8      // in_units
#define ISZ  1152   // in_size
#define JJ   10     // out_units
#define DD   16     // out_size
#define JD   (JJ*DD)      // 160
#define K1   (UU*ISZ)     // 9216 ; sgemm k-order: k = i*8+u
#define ICH  16           // i per sgemm block-job
#define NIC  (ISZ/ICH)    // 72 split-K parts
#define GRID 512
#define FSTR 32           // flag stride in ints: one 128B cacheline per block

typedef short v8s __attribute__((ext_vector_type(8)));   // 8 bf16 in 4 VGPRs
typedef float f4v __attribute__((ext_vector_type(4)));   // mfma accumulator
typedef unsigned short ush;

__device__ __forceinline__ ush f2bf(float f) {
    unsigned int u = __float_as_uint(f);
    unsigned int r = (u + 0x7fffu + ((u >> 16) & 1u)) >> 16;   // RNE
    return (ush)r;
}
__device__ __forceinline__ float bf2f(ush h) {
    return __uint_as_float(((unsigned int)h) << 16);
}
__device__ __forceinline__ float aload(const float* p) {
    return __hip_atomic_load(p, __ATOMIC_RELAXED, __HIP_MEMORY_SCOPE_AGENT);
}

// Grid barrier v3: ONE CACHELINE PER FLAG. Arrive-stores are fully parallel
// (no line-ownership migration between XCDs). Block 0 scans in parallel, then
// publishes a release word that other blocks only READ (shared line, no RMW).
__device__ __forceinline__ void gbar(volatile int* flags, volatile int* rel, int ep) {
    __syncthreads();
    if (threadIdx.x == 0)
        __hip_atomic_store((int*)&flags[blockIdx.x * FSTR], ep,
                           __ATOMIC_RELEASE, __HIP_MEMORY_SCOPE_AGENT);
    if (blockIdx.x == 0) {
        for (int i = threadIdx.x; i < GRID; i += 256)
            while (__hip_atomic_load((int*)&flags[i * FSTR],
                                     __ATOMIC_ACQUIRE, __HIP_MEMORY_SCOPE_AGENT) < ep)
                __builtin_amdgcn_s_sleep(1);
        __syncthreads();
        if (threadIdx.x == 0)
            __hip_atomic_store((int*)rel, ep, __ATOMIC_RELEASE, __HIP_MEMORY_SCOPE_AGENT);
    } else if (threadIdx.x == 0) {
        while (__hip_atomic_load((int*)rel, __ATOMIC_ACQUIRE,
                                 __HIP_MEMORY_SCOPE_AGENT) < ep)
            __builtin_amdgcn_s_sleep(4);
    }
    __syncthreads();
}

union __align__(16) SMem {
    float prep_buf[16][8][65];                        // 33.3 KB (max member)
    struct {
        ush bh[2][16][136];                           // B^T hi [jj][d][k_local]
        ush bl[2][16][136];                           // B^T lo
        float c[2][ICH];
        float redm[4], reds[4];
    } sg;
    float sm[JD];
};

__global__ __launch_bounds__(256, 2) void capsule_persist(
        const float* __restrict__ x, const float* __restrict__ W,
        float* __restrict__ v_out, int* flags, int* rel,
        float* __restrict__ b_ij, float* __restrict__ s_part,
        ush* __restrict__ xsh, ush* __restrict__ xsl,
        ush* __restrict__ xth, ush* __restrict__ xtl,
        ush* __restrict__ vth, ush* __restrict__ vtl) {
    __shared__ SMem smem;
    int bid = blockIdx.x;
    int t = threadIdx.x, lane = t & 63, wv = t >> 6;
    int col = lane & 15, q = lane >> 4;
    int ep = 0;

    // ---- P0: prep x -> xs[i][b*8+u] + xt[u*1152+i][b] (bf16-split); b_ij = 1 ----
    if (bid < 45) b_ij[bid * 256 + t] = 1.0f;         // 45*256 = 11520
    if (bid < 288) {
        int itile = bid % 18, btile = bid / 18;       // 18 i-tiles x 16 b-tiles
        int i0 = itile * 64, b0 = btile * 16;
        for (int rep = 0; rep < 32; ++rep) {
            int row = rep * 4 + wv;                   // 0..127 = (bl,u)
            int bl = row >> 3, u = row & 7;
            smem.prep_buf[bl][u][lane] =
                x[(size_t)(b0 + bl) * K1 + (size_t)u * ISZ + i0 + lane];
        }
        __syncthreads();
        {   // xs[i][b*8+u]
            int half = t >> 7, bl = (t & 127) >> 3, u = t & 7;
            for (int il = half * 32; il < half * 32 + 32; ++il) {
                float v = smem.prep_buf[bl][u][il];
                ush h = f2bf(v);
                size_t o = (size_t)(i0 + il) * 2048 + (size_t)(b0 + bl) * 8 + u;
                xsh[o] = h; xsl[o] = f2bf(v - bf2f(h));
            }
        }
        {   // xt[u*1152+i][b]
            int bl = t & 15, r = t >> 4;
            for (int pass = 0; pass < 32; ++pass) {
                int row = pass * 16 + r;              // 0..511 = (u,il)
                int u = row >> 6, il = row & 63;
                float v = smem.prep_buf[bl][u][il];
                ush h = f2bf(v);
                size_t o = (size_t)(u * ISZ + i0 + il) * BB + b0 + bl;
                xth[o] = h; xtl[o] = f2bf(v - bf2f(h));
            }
        }
    }
    gbar(flags, rel, ++ep);

    for (int it = 0; it < 3; ++it) {
        // ---- P1: sgemm (R11-verified): 360 jobs of 2 j x 16 i ----
        if (bid < 360) {
            int jh = bid % 5, ic = bid / 5;
            int j0 = jh * 2, i0 = ic * ICH;

            if (it == 0) {
                if (t < 2 * ICH) smem.sg.c[t >> 4][t & 15] = 1.0f / 1152.0f;
            } else {
                for (int jj = 0; jj < 2; ++jj) {
                    const float* bp = b_ij + (size_t)(j0 + jj) * ISZ;
                    float m = -1e30f;
                    for (int k = t; k < ISZ; k += 256) m = fmaxf(m, aload(bp + k));
#pragma unroll
                    for (int off = 32; off; off >>= 1) m = fmaxf(m, __shfl_down(m, off, 64));
                    if (lane == 0) smem.sg.redm[wv] = m;
                    __syncthreads();
                    m = fmaxf(fmaxf(smem.sg.redm[0], smem.sg.redm[1]),
                              fmaxf(smem.sg.redm[2], smem.sg.redm[3]));
                    float ss = 0.f;
                    for (int k = t; k < ISZ; k += 256) ss += __expf(aload(bp + k) - m);
#pragma unroll
                    for (int off = 32; off; off >>= 1) ss += __shfl_down(ss, off, 64);
                    if (lane == 0) smem.sg.reds[wv] = ss;
                    __syncthreads();
                    float inv = 1.f / (smem.sg.reds[0] + smem.sg.reds[1]
                                       + smem.sg.reds[2] + smem.sg.reds[3]);
                    if (t < ICH) smem.sg.c[jj][t] = __expf(aload(bp + i0 + t) - m) * inv;
                    __syncthreads();
                }
            }
            __syncthreads();

            for (int slot = t; slot < 512; slot += 256) {   // build B tiles
                int jj = slot >> 8, rem = slot & 255, ii = rem >> 4, d = rem & 15;
                const float* wp = W + (size_t)(i0 + ii) * 1280 + (j0 + jj) * 128 + d * 8;
                float4 wa = *(const float4*)wp;
                float4 wb = *(const float4*)(wp + 4);
                float ci = smem.sg.c[jj][ii];
                float vals[8] = { wa.x * ci, wa.y * ci, wa.z * ci, wa.w * ci,
                                  wb.x * ci, wb.y * ci, wb.z * ci, wb.w * ci };
                v8s hv, lv;
#pragma unroll
                for (int u = 0; u < 8; ++u) {
                    ush h = f2bf(vals[u]);
                    hv[u] = (short)h;
                    lv[u] = (short)f2bf(vals[u] - bf2f(h));
                }
                *(v8s*)&smem.sg.bh[jj][d][ii * 8] = hv;
                *(v8s*)&smem.sg.bl[jj][d][ii * 8] = lv;
            }
            __syncthreads();

            int m_base = wv * 64;
            f4v acc[4][2];
#pragma unroll
            for (int mm = 0; mm < 4; ++mm)
#pragma unroll
                for (int jj = 0; jj < 2; ++jj) acc[mm][jj] = (f4v){0.f, 0.f, 0.f, 0.f};
#pragma unroll
            for (int s = 0; s < 4; ++s) {
                v8s bh0 = *(const v8s*)&smem.sg.bh[0][col][s * 32 + q * 8];
                v8s bl0 = *(const v8s*)&smem.sg.bl[0][col][s * 32 + q * 8];
                v8s bh1 = *(const v8s*)&smem.sg.bh[1][col][s * 32 + q * 8];
                v8s bl1 = *(const v8s*)&smem.sg.bl[1][col][s * 32 + q * 8];
                size_t abase = (size_t)(i0 + s * 4 + q) * 2048;
#pragma unroll
                for (int mm = 0; mm < 4; ++mm) {
                    size_t ao = abase + (size_t)(m_base + mm * 16 + col) * 8;
                    v8s ah = *(const v8s*)(xsh + ao);
                    v8s al = *(const v8s*)(xsl + ao);
                    acc[mm][0] = __builtin_amdgcn_mfma_f32_16x16x32_bf16(ah, bh0, acc[mm][0], 0, 0, 0);
                    acc[mm][0] = __builtin_amdgcn_mfma_f32_16x16x32_bf16(ah, bl0, acc[mm][0], 0, 0, 0);
                    acc[mm][0] = __builtin_amdgcn_mfma_f32_16x16x32_bf16(al, bh0, acc[mm][0], 0, 0, 0);
                    acc[mm][1] = __builtin_amdgcn_mfma_f32_16x16x32_bf16(ah, bh1, acc[mm][1], 0, 0, 0);
                    acc[mm][1] = __builtin_amdgcn_mfma_f32_16x16x32_bf16(ah, bl1, acc[mm][1], 0, 0, 0);
                    acc[mm][1] = __builtin_amdgcn_mfma_f32_16x16x32_bf16(al, bh1, acc[mm][1], 0, 0, 0);
                }
            }
#pragma unroll
            for (int mm = 0; mm < 4; ++mm)
#pragma unroll
                for (int jj = 0; jj < 2; ++jj)
#pragma unroll
                    for (int r = 0; r < 4; ++r)
                        s_part[((size_t)ic * BB + m_base + mm * 16 + q * 4 + r) * JD
                               + (j0 + jj) * DD + col] = acc[mm][jj][r];
        }
        gbar(flags, rel, ++ep);

        // ---- P2: reduce split-K + squash; v_out + vT bf16-split ----
        if (bid < BB) {
            int b = bid;
            if (t < JD) {
                float s = 0.f;
#pragma unroll 8
                for (int p = 0; p < NIC; ++p) s += s_part[((size_t)p * BB + b) * JD + t];
                smem.sm[t] = s;
            }
            __syncthreads();
            if (t < JD) {
                int d = t & 15;
                float msq = 0.f;
#pragma unroll
                for (int j = 0; j < JJ; ++j) { float xx = smem.sm[j * DD + d]; msq += xx * xx; }
                float val = msq / (1.f + msq) * smem.sm[t] * rsqrtf(msq);
                v_out[(size_t)b * JD + t] = val;
                ush h = f2bf(val);
                vth[(size_t)t * BB + b] = h;
                vtl[(size_t)t * BB + b] = f2bf(val - bf2f(h));
            }
        }
        if (it == 2) break;               // final iteration: v_out done
        gbar(flags, rel, ++ep);

        // ---- P3: mgemm (vT @ x, K=256) + agreement epilogue [R7-verified] ----
        for (int job = bid; job < 1440; job += GRID) {
            int wj = job * 4 + wv;        // 5760 wave-jobs
            int mt = wj / 576, nt = wj % 576;
            int m0 = mt * 16, n0 = nt * 16;
            size_t aoff = (size_t)(m0 + col) * BB + q * 8;
            size_t boff = (size_t)(n0 + col) * BB + q * 8;
            f4v acc = {0.f, 0.f, 0.f, 0.f};
#pragma unroll
            for (int s = 0; s < BB / 32; ++s) {
                v8s ah = *(const v8s*)(vth + aoff);
                v8s al = *(const v8s*)(vtl + aoff);
                v8s bh = *(const v8s*)(xth + boff);
                v8s bl = *(const v8s*)(xtl + boff);
                acc = __builtin_amdgcn_mfma_f32_16x16x32_bf16(ah, bh, acc, 0, 0, 0);
                acc = __builtin_amdgcn_mfma_f32_16x16x32_bf16(ah, bl, acc, 0, 0, 0);
                acc = __builtin_amdgcn_mfma_f32_16x16x32_bf16(al, bh, acc, 0, 0, 0);
                aoff += 32; boff += 32;
            }
            int u = nt / 72;
            int i = (nt % 72) * 16 + col;
            const float* Wp = W + (size_t)i * 1280 + mt * 128 + q * 32 + u;
            float p = Wp[0] * acc[0] + Wp[8] * acc[1] + Wp[16] * acc[2] + Wp[24] * acc[3];
            p += __shfl_xor(p, 16, 64);
            p += __shfl_xor(p, 32, 64);
            if (q == 0) atomicAdd(&b_ij[(size_t)mt * ISZ + i], p * (1.0f / 256.0f));
        }
        gbar(flags, rel, ++ep);
    }
}

extern "C" void kernel_launch(void* const* d_in, const int* in_sizes, int n_in,
                              void* d_out, int out_size, void* d_ws, size_t ws_size,
                              hipStream_t stream) {
    const float* x = (const float*)d_in[0];   // (256, 8, 1152)
    const float* W = (const float*)d_in[1];   // (1, 1152, 10, 16, 8)
    float* v_out = (float*)d_out;             // (256, 10, 16, 1)

    int*   flags  = (int*)d_ws;                            // GRID lines, 128B apart
    int*   rel    = flags + GRID * FSTR;                   // own line
    float* b_ij   = (float*)d_ws + GRID * FSTR + 64;       // 11,520 f (16B-aligned)
    float* s_part = b_ij + ISZ * JJ;                       // 72*256*160 f
    ush* xsh = (ush*)(s_part + (size_t)NIC * BB * JD);     // [1152][2048]
    ush* xsl = xsh + (size_t)ISZ * 2048;
    ush* xth = xsl + (size_t)ISZ * 2048;                   // [9216][256]
    ush* xtl = xth + (size_t)K1 * BB;
    ush* vth = xtl + (size_t)K1 * BB;                      // [160][256]
    ush* vtl = vth + (size_t)JD * BB;

    hipMemsetAsync(flags, 0, (GRID * FSTR + 64) * sizeof(int), stream);
    hipLaunchKernelGGL(capsule_persist, dim3(GRID), dim3(256), 0, stream,
                       x, W, v_out, flags, rel, b_ij, s_part,
                       xsh, xsl, xth, xtl, vth, vtl);
}

// Round 15
// 183.532 us; speedup vs baseline: 3.9325x; 3.9325x over previous
//
#include <hip/hip_runtime.h>
#include <cstddef>

#define BB   256    // batch = GEMM1 M
#define UU   8      // in_units
#define ISZ  1152   // in_size
#define JJ   10     // out_units
#define DD   16     // out_size
#define JD   (JJ*DD)      // 160
#define K1   (UU*ISZ)     // 9216 ; sgemm k-order: k = i*8+u
#define ICH  16           // i per sgemm block
#define NIC  (ISZ/ICH)    // 72  (split-K part count)
#define NJH  5            // j-pairs

typedef short v8s __attribute__((ext_vector_type(8)));   // 8 bf16 in 4 VGPRs
typedef float f4v __attribute__((ext_vector_type(4)));   // mfma accumulator
typedef unsigned short ush;

__device__ __forceinline__ ush f2bf(float f) {
    unsigned int u = __float_as_uint(f);
    unsigned int r = (u + 0x7fffu + ((u >> 16) & 1u)) >> 16;   // RNE
    return (ush)r;
}
__device__ __forceinline__ float bf2f(ush h) {
    return __uint_as_float(((unsigned int)h) << 16);
}

// ---------------- prep: x[b,u,i] -> xs[i][b*8+u] (split) + xt[u*1152+i][b] (split); b_ij=1 ----
__global__ void prep_kernel(const float* __restrict__ x,
                            ush* __restrict__ xsh, ush* __restrict__ xsl,
                            ush* __restrict__ xth, ush* __restrict__ xtl,
                            float* __restrict__ b_ij) {
    __shared__ float buf[32][8][65];
    int it = blockIdx.x;            // 18 tiles of 64 i
    int bt = blockIdx.y;            // 8 tiles of 32 b
    int i0 = it * 64, b0 = bt * 32;
    int t = threadIdx.x, lane = t & 63, wv = t >> 6;

    int flat = bt * 18 + it;
    if (flat < 45) b_ij[flat * 256 + t] = 1.0f;   // 45*256 = 11520

    for (int rep = 0; rep < 64; ++rep) {
        int row = rep * 4 + wv;     // 0..255 = (bl,u)
        int bl = row >> 3, u = row & 7;
        buf[bl][u][lane] = x[(size_t)(b0 + bl) * K1 + (size_t)u * ISZ + i0 + lane];
    }
    __syncthreads();
    {   // xs[i][b*8+u]
        int bl = t >> 3, u = t & 7;
        for (int il = 0; il < 64; ++il) {
            float v = buf[bl][u][il];
            ush h = f2bf(v);
            size_t o = (size_t)(i0 + il) * 2048 + (size_t)(b0 + bl) * 8 + u;
            xsh[o] = h; xsl[o] = f2bf(v - bf2f(h));
        }
    }
    {   // xt[u*1152+i][b]
        int g = t >> 5, bl = t & 31;
        for (int pass = 0; pass < 64; ++pass) {
            int cu = pass * 8 + g;
            int u = cu >> 6, il = cu & 63;
            float v = buf[bl][u][il];
            ush h = f2bf(v);
            size_t o = (size_t)(u * ISZ + i0 + il) * BB + b0 + bl;
            xth[o] = h; xtl[o] = f2bf(v - bf2f(h));
        }
    }
}

// ---------------- sgemm: s_part[ic][b][jd] for 2 j x 16 i per block ----------------
// grid (NIC, NJH) = (72, 5): the 5 blocks sharing an A-slice (same ic) are 72 apart
// -> same bid%8 -> same XCD -> A-slice L2-shared (vs R11's 5x HBM refetch).
__global__ __launch_bounds__(256, 2) void sgemm_fused(
        const ush* __restrict__ xsh, const ush* __restrict__ xsl,
        const float* __restrict__ W, const float* __restrict__ b_ij,
        float* __restrict__ s_part, int first) {
    int ic = blockIdx.x, jh = blockIdx.y;
    int j0 = jh * 2, i0 = ic * ICH;
    int t = threadIdx.x, lane = t & 63, wv = t >> 6;
    int col = lane & 15, q = lane >> 4;

    __shared__ __align__(16) ush bh_[2][16][136];   // B^T hi [jj][d][k_local]
    __shared__ __align__(16) ush bl_[2][16][136];   // B^T lo
    __shared__ float c_lds[2][ICH];
    __shared__ float redm[4], reds[4];

    if (first) {
        if (t < 2 * ICH) c_lds[t >> 4][t & 15] = 1.0f / 1152.0f;
    } else {
        // parallel softmax: waves 0-1 -> jj=0, waves 2-3 -> jj=1
        int jj = wv >> 1, half = wv & 1;
        const float* bp = b_ij + (size_t)(j0 + jj) * ISZ;
        float m = -1e30f;
        for (int k = half * 64 + lane; k < ISZ; k += 128) m = fmaxf(m, bp[k]);
#pragma unroll
        for (int off = 32; off; off >>= 1) m = fmaxf(m, __shfl_down(m, off, 64));
        if (lane == 0) redm[wv] = m;
        __syncthreads();
        m = fmaxf(redm[jj * 2], redm[jj * 2 + 1]);
        float ss = 0.f;
        for (int k = half * 64 + lane; k < ISZ; k += 128) ss += __expf(bp[k] - m);
#pragma unroll
        for (int off = 32; off; off >>= 1) ss += __shfl_down(ss, off, 64);
        if (lane == 0) reds[wv] = ss;
        __syncthreads();
        if (t < 2 * ICH) {
            int cj = t >> 4, ci = t & 15;
            float mj = fmaxf(redm[cj * 2], redm[cj * 2 + 1]);
            float inv = 1.f / (reds[cj * 2] + reds[cj * 2 + 1]);
            c_lds[cj][ci] = __expf(b_ij[(size_t)(j0 + cj) * ISZ + i0 + ci] - mj) * inv;
        }
    }
    __syncthreads();

    // build B tiles: 512 slots = (jj, ii, d), 2 per thread
    for (int slot = t; slot < 512; slot += 256) {
        int jj = slot >> 8, rem = slot & 255, ii = rem >> 4, d = rem & 15;
        const float* wp = W + (size_t)(i0 + ii) * 1280 + (j0 + jj) * 128 + d * 8;
        float4 wa = *(const float4*)wp;
        float4 wb = *(const float4*)(wp + 4);
        float ci = c_lds[jj][ii];
        float vals[8] = { wa.x * ci, wa.y * ci, wa.z * ci, wa.w * ci,
                          wb.x * ci, wb.y * ci, wb.z * ci, wb.w * ci };
        v8s hv, lv;
#pragma unroll
        for (int u = 0; u < 8; ++u) {
            ush h = f2bf(vals[u]);
            hv[u] = (short)h;
            lv[u] = (short)f2bf(vals[u] - bf2f(h));
        }
        *(v8s*)&bh_[jj][d][ii * 8] = hv;
        *(v8s*)&bl_[jj][d][ii * 8] = lv;
    }
    __syncthreads();

    int m_base = wv * 64;
    f4v acc[4][2];
#pragma unroll
    for (int mm = 0; mm < 4; ++mm)
#pragma unroll
        for (int jj = 0; jj < 2; ++jj) acc[mm][jj] = (f4v){0.f, 0.f, 0.f, 0.f};

#pragma unroll
    for (int s = 0; s < 4; ++s) {           // 4 k-steps x 32 k = 128 k (16 i)
        v8s bh0 = *(const v8s*)&bh_[0][col][s * 32 + q * 8];
        v8s bl0 = *(const v8s*)&bl_[0][col][s * 32 + q * 8];
        v8s bh1 = *(const v8s*)&bh_[1][col][s * 32 + q * 8];
        v8s bl1 = *(const v8s*)&bl_[1][col][s * 32 + q * 8];
        size_t abase = (size_t)(i0 + s * 4 + q) * 2048;
#pragma unroll
        for (int mm = 0; mm < 4; ++mm) {
            size_t ao = abase + (size_t)(m_base + mm * 16 + col) * 8;
            v8s ah = *(const v8s*)(xsh + ao);
            v8s al = *(const v8s*)(xsl + ao);
            acc[mm][0] = __builtin_amdgcn_mfma_f32_16x16x32_bf16(ah, bh0, acc[mm][0], 0, 0, 0);
            acc[mm][0] = __builtin_amdgcn_mfma_f32_16x16x32_bf16(ah, bl0, acc[mm][0], 0, 0, 0);
            acc[mm][0] = __builtin_amdgcn_mfma_f32_16x16x32_bf16(al, bh0, acc[mm][0], 0, 0, 0);
            acc[mm][1] = __builtin_amdgcn_mfma_f32_16x16x32_bf16(ah, bh1, acc[mm][1], 0, 0, 0);
            acc[mm][1] = __builtin_amdgcn_mfma_f32_16x16x32_bf16(ah, bl1, acc[mm][1], 0, 0, 0);
            acc[mm][1] = __builtin_amdgcn_mfma_f32_16x16x32_bf16(al, bh1, acc[mm][1], 0, 0, 0);
        }
    }
    // C/D: col = n, row = q*4+r (= b within m-tile)  [R7-verified]
#pragma unroll
    for (int mm = 0; mm < 4; ++mm)
#pragma unroll
        for (int jj = 0; jj < 2; ++jj)
#pragma unroll
            for (int r = 0; r < 4; ++r)
                s_part[((size_t)ic * BB + m_base + mm * 16 + q * 4 + r) * JD
                       + (j0 + jj) * DD + col] = acc[mm][jj][r];
}

// ---------------- reduce split-K + squash; v_out, vT bf16-split ----------------
__global__ void reduce_squash(const float* __restrict__ s_part, float* __restrict__ v,
                              ush* __restrict__ vth, ush* __restrict__ vtl) {
    int b = blockIdx.x, t = threadIdx.x;   // 192, t<160 active
    __shared__ float sm[JD];
    if (t < JD) {
        float s = 0.f;
#pragma unroll 8
        for (int p = 0; p < NIC; ++p) s += s_part[((size_t)p * BB + b) * JD + t];
        sm[t] = s;
    }
    __syncthreads();
    if (t < JD) {
        int d = t & 15;
        float msq = 0.f;
#pragma unroll
        for (int j = 0; j < JJ; ++j) { float xx = sm[j * DD + d]; msq += xx * xx; }
        float val = msq / (1.f + msq) * sm[t] * rsqrtf(msq);
        v[(size_t)b * JD + t] = val;
        ush h = f2bf(val);
        vth[(size_t)t * BB + b] = h;
        vtl[(size_t)t * BB + b] = f2bf(val - bf2f(h));
    }
}

// ---------------- mgemm + agreement epilogue [R7-verified]; 2 jobs per wave ----------------
__global__ __launch_bounds__(256) void mgemm_agree(
        const ush* __restrict__ Ah, const ush* __restrict__ Al,
        const ush* __restrict__ Bh, const ush* __restrict__ Bl,
        const float* __restrict__ W, float* __restrict__ b_ij) {
    int w = threadIdx.x >> 6, lane = threadIdx.x & 63;
    int col = lane & 15, q = lane >> 4;
    int wbase = blockIdx.x * 4 + w;     // 720 blocks -> waves 0..2879
#pragma unroll
    for (int rep = 0; rep < 2; ++rep) {
        int wj = wbase + rep * 2880;    // 5760 wave-jobs
        int mt = wj / 576, nt = wj % 576;
        int m0 = mt * 16, n0 = nt * 16;
        size_t aoff = (size_t)(m0 + col) * BB + q * 8;
        size_t boff = (size_t)(n0 + col) * BB + q * 8;
        f4v acc = {0.f, 0.f, 0.f, 0.f};
#pragma unroll
        for (int s = 0; s < BB / 32; ++s) {
            v8s ah = *(const v8s*)(Ah + aoff);
            v8s al = *(const v8s*)(Al + aoff);
            v8s bh = *(const v8s*)(Bh + boff);
            v8s bl = *(const v8s*)(Bl + boff);
            acc = __builtin_amdgcn_mfma_f32_16x16x32_bf16(ah, bh, acc, 0, 0, 0);
            acc = __builtin_amdgcn_mfma_f32_16x16x32_bf16(ah, bl, acc, 0, 0, 0);
            acc = __builtin_amdgcn_mfma_f32_16x16x32_bf16(al, bh, acc, 0, 0, 0);
            aoff += 32; boff += 32;
        }
        int u = nt / 72;
        int i = (nt % 72) * 16 + col;
        const float* Wp = W + (size_t)i * 1280 + mt * 128 + q * 32 + u;
        float p = Wp[0] * acc[0] + Wp[8] * acc[1] + Wp[16] * acc[2] + Wp[24] * acc[3];
        p += __shfl_xor(p, 16, 64);
        p += __shfl_xor(p, 32, 64);
        if (q == 0) atomicAdd(&b_ij[(size_t)mt * ISZ + i], p * (1.0f / 256.0f));
    }
}

extern "C" void kernel_launch(void* const* d_in, const int* in_sizes, int n_in,
                              void* d_out, int out_size, void* d_ws, size_t ws_size,
                              hipStream_t stream) {
    const float* x = (const float*)d_in[0];   // (256, 8, 1152)
    const float* W = (const float*)d_in[1];   // (1, 1152, 10, 16, 8)
    float* v_out = (float*)d_out;             // (256, 10, 16, 1)

    float* b_ij   = (float*)d_ws;                          // 11,520 f
    float* s_part = b_ij + ISZ * JJ;                       // 72*256*160 = 2,949,120 f
    ush* xsh = (ush*)(s_part + (size_t)NIC * BB * JD);     // [1152][2048]
    ush* xsl = xsh + (size_t)ISZ * 2048;
    ush* xth = xsl + (size_t)ISZ * 2048;                   // [9216][256]
    ush* xtl = xth + (size_t)K1 * BB;
    ush* vth = xtl + (size_t)K1 * BB;                      // [160][256]
    ush* vtl = vth + (size_t)JD * BB;

    hipLaunchKernelGGL(prep_kernel, dim3(18, 8), dim3(256), 0, stream,
                       x, xsh, xsl, xth, xtl, b_ij);
    for (int it = 0; it < 3; ++it) {
        hipLaunchKernelGGL(sgemm_fused, dim3(NIC, NJH), dim3(256), 0, stream,
                           xsh, xsl, W, b_ij, s_part, it == 0 ? 1 : 0);
        hipLaunchKernelGGL(reduce_squash, dim3(BB), dim3(192), 0, stream,
                           s_part, v_out, vth, vtl);
        if (it < 2) {
            hipLaunchKernelGGL(mgemm_agree, dim3(720), dim3(256), 0, stream,
                               vth, vtl, xth, xtl, W, b_ij);
        }
    }
}